// Round 1
// baseline (5222.260 us; speedup 1.0000x reference)
//
#include <hip/hip_runtime.h>
#include <math.h>

#define N_NODES 20000
#define HD      128
#define H3      384
#define RDIM    32
#define E_EDGES 320000
#define WIN     416   // 3H + R

#define INV_SQRT_3 0.57735026918962576f
#define INV_SQRT_H 0.08838834764831845f

__device__ __forceinline__ float silu_f(float x) {
    return x / (1.0f + expf(-x));
}

// ---------------------------------------------------------------- LayerNorm
__global__ __launch_bounds__(256)
void ln_kernel(const float* __restrict__ x, const float* __restrict__ w,
               const float* __restrict__ b, float* __restrict__ out) {
    int row  = blockIdx.x * 4 + (threadIdx.x >> 6);
    int lane = threadIdx.x & 63;
    if (row >= N_NODES) return;
    const float* xr = x + (size_t)row * HD;
    float v0 = xr[lane], v1 = xr[lane + 64];
    float s = v0 + v1;
    #pragma unroll
    for (int o = 32; o > 0; o >>= 1) s += __shfl_xor(s, o, 64);
    float mu = s * (1.0f / 128.0f);
    float d0 = v0 - mu, d1 = v1 - mu;
    float vs = d0 * d0 + d1 * d1;
    #pragma unroll
    for (int o = 32; o > 0; o >>= 1) vs += __shfl_xor(vs, o, 64);
    float rstd = rsqrtf(vs * (1.0f / 128.0f) + 1e-5f);
    out[(size_t)row * HD + lane]      = d0 * rstd * w[lane]      + b[lane];
    out[(size_t)row * HD + lane + 64] = d1 * rstd * w[lane + 64] + b[lane + 64];
}

// ---------------------------------------------------------------- Tiled f32 GEMM
// C[M,Nfull-slice] = epi(A[M,K] @ B[K,Nfull] + bias)
// tile: 64 rows x 128 cols, 256 threads, 4x8 per thread, Kblk=32
// EPI: 0 = none, 1 = silu, 2 = bias + silu
template<int EPI>
__global__ __launch_bounds__(256)
void gemm_tiled(const float* __restrict__ A, const float* __restrict__ B,
                const float* __restrict__ bias, float* __restrict__ C,
                int M, int K, int Nfull) {
    __shared__ float As[64][36];   // padded: f4-aligned rows, <=2-way read conflicts
    __shared__ float Bs[32][128];

    const int rowBase = blockIdx.x * 64;
    const int colBase = blockIdx.y * 128;
    const int tid = threadIdx.x;
    const int ty  = tid >> 4;        // 0..15 -> rows ty*4..ty*4+3
    const int tx  = tid & 15;        // 0..15 -> cols tx*4 + {0..3} and +64
    const int ty4 = ty << 2;
    const int txc = tx << 2;

    float acc[4][8];
    #pragma unroll
    for (int i = 0; i < 4; ++i)
        #pragma unroll
        for (int j = 0; j < 8; ++j) acc[i][j] = 0.0f;

    const int nK = K >> 5;
    for (int ko = 0; ko < nK; ++ko) {
        const int kBase = ko << 5;
        // A tile: 64x32
        #pragma unroll
        for (int q = 0; q < 2; ++q) {
            int v  = tid + (q << 8);
            int r  = v >> 3;
            int c4 = (v & 7) << 2;
            float4 val = make_float4(0.f, 0.f, 0.f, 0.f);
            int gr = rowBase + r;
            if (gr < M) val = *(const float4*)(A + (size_t)gr * K + kBase + c4);
            *(float4*)&As[r][c4] = val;
        }
        // B tile: 32x128
        #pragma unroll
        for (int q = 0; q < 4; ++q) {
            int v  = tid + (q << 8);
            int r  = v >> 5;
            int c4 = (v & 31) << 2;
            *(float4*)&Bs[r][c4] =
                *(const float4*)(B + (size_t)(kBase + r) * Nfull + colBase + c4);
        }
        __syncthreads();
        #pragma unroll
        for (int k = 0; k < 32; ++k) {
            float av[4];
            #pragma unroll
            for (int i = 0; i < 4; ++i) av[i] = As[ty4 + i][k];
            float bv[8];
            *(float4*)&bv[0] = *(const float4*)&Bs[k][txc];
            *(float4*)&bv[4] = *(const float4*)&Bs[k][txc + 64];
            #pragma unroll
            for (int i = 0; i < 4; ++i)
                #pragma unroll
                for (int j = 0; j < 8; ++j)
                    acc[i][j] = fmaf(av[i], bv[j], acc[i][j]);
        }
        __syncthreads();
    }

    #pragma unroll
    for (int i = 0; i < 4; ++i) {
        int gr = rowBase + ty4 + i;
        if (gr >= M) continue;
        #pragma unroll
        for (int half = 0; half < 2; ++half) {
            int gc = colBase + txc + half * 64;
            float o[4];
            #pragma unroll
            for (int j = 0; j < 4; ++j) {
                float v = acc[i][half * 4 + j];
                if (EPI == 2) v += bias[gc + j];
                if (EPI >= 1) v = silu_f(v);
                o[j] = v;
            }
            *(float4*)(C + (size_t)gr * Nfull + gc) =
                make_float4(o[0], o[1], o[2], o[3]);
        }
    }
}

// ---------------------------------------------------------------- edge GEMM2 fused
// m[e, :] = (xh[jj]+xh[ii]) * (edge_rbf @ rbf_w) * (d1 @ dir_w2 + b2)
__global__ __launch_bounds__(256)
void edge2_fused(const float* __restrict__ d1, const float* __restrict__ w2,
                 const float* __restrict__ b2,
                 const float* __restrict__ edge_rbf, const float* __restrict__ rbf_w,
                 const float* __restrict__ xh, const int* __restrict__ ei,
                 float* __restrict__ m_out, int chunkOff, int Mrows) {
    __shared__ float As[64][36];
    __shared__ float Bs[32][128];

    const int rowBase = blockIdx.x * 64;
    const int colBase = blockIdx.y * 128;
    const int tid = threadIdx.x;
    const int ty4 = (tid >> 4) << 2;
    const int txc = (tid & 15) << 2;

    float acc[4][8];
    #pragma unroll
    for (int i = 0; i < 4; ++i)
        #pragma unroll
        for (int j = 0; j < 8; ++j) acc[i][j] = 0.0f;

    // main K=384 loop over d1 @ dir_w2
    for (int ko = 0; ko < (H3 >> 5); ++ko) {
        const int kBase = ko << 5;
        #pragma unroll
        for (int q = 0; q < 2; ++q) {
            int v = tid + (q << 8);
            int r = v >> 3, c4 = (v & 7) << 2;
            float4 val = make_float4(0.f, 0.f, 0.f, 0.f);
            int gr = rowBase + r;
            if (gr < Mrows) val = *(const float4*)(d1 + (size_t)gr * H3 + kBase + c4);
            *(float4*)&As[r][c4] = val;
        }
        #pragma unroll
        for (int q = 0; q < 4; ++q) {
            int v = tid + (q << 8);
            int r = v >> 5, c4 = (v & 31) << 2;
            *(float4*)&Bs[r][c4] =
                *(const float4*)(w2 + (size_t)(kBase + r) * H3 + colBase + c4);
        }
        __syncthreads();
        #pragma unroll
        for (int k = 0; k < 32; ++k) {
            float av[4];
            #pragma unroll
            for (int i = 0; i < 4; ++i) av[i] = As[ty4 + i][k];
            float bv[8];
            *(float4*)&bv[0] = *(const float4*)&Bs[k][txc];
            *(float4*)&bv[4] = *(const float4*)&Bs[k][txc + 64];
            #pragma unroll
            for (int i = 0; i < 4; ++i)
                #pragma unroll
                for (int j = 0; j < 8; ++j)
                    acc[i][j] = fmaf(av[i], bv[j], acc[i][j]);
        }
        __syncthreads();
    }

    // rbf phase: racc = edge_rbf[rows,32] @ rbf_w[32, coltile]
    #pragma unroll
    for (int q = 0; q < 2; ++q) {
        int v = tid + (q << 8);
        int r = v >> 3, c4 = (v & 7) << 2;
        float4 val = make_float4(0.f, 0.f, 0.f, 0.f);
        int gr = rowBase + r;
        if (gr < Mrows)
            val = *(const float4*)(edge_rbf + (size_t)(chunkOff + gr) * RDIM + c4);
        *(float4*)&As[r][c4] = val;
    }
    #pragma unroll
    for (int q = 0; q < 4; ++q) {
        int v = tid + (q << 8);
        int r = v >> 5, c4 = (v & 31) << 2;
        *(float4*)&Bs[r][c4] =
            *(const float4*)(rbf_w + (size_t)r * H3 + colBase + c4);
    }
    __syncthreads();

    float racc[4][8];
    #pragma unroll
    for (int i = 0; i < 4; ++i)
        #pragma unroll
        for (int j = 0; j < 8; ++j) racc[i][j] = 0.0f;
    #pragma unroll
    for (int k = 0; k < 32; ++k) {
        float av[4];
        #pragma unroll
        for (int i = 0; i < 4; ++i) av[i] = As[ty4 + i][k];
        float bv[8];
        *(float4*)&bv[0] = *(const float4*)&Bs[k][txc];
        *(float4*)&bv[4] = *(const float4*)&Bs[k][txc + 64];
        #pragma unroll
        for (int i = 0; i < 4; ++i)
            #pragma unroll
            for (int j = 0; j < 8; ++j)
                racc[i][j] = fmaf(av[i], bv[j], racc[i][j]);
    }

    // epilogue: gather xh, combine, write m
    #pragma unroll
    for (int i = 0; i < 4; ++i) {
        int gr = rowBase + ty4 + i;
        if (gr >= Mrows) continue;
        int e = chunkOff + gr;
        int jjv = ei[e], iiv = ei[E_EDGES + e];
        const float* xj = xh + (size_t)jjv * H3;
        const float* xi = xh + (size_t)iiv * H3;
        #pragma unroll
        for (int half = 0; half < 2; ++half) {
            int gc = colBase + txc + half * 64;
            float4 bj = *(const float4*)(xj + gc);
            float4 bi = *(const float4*)(xi + gc);
            float4 bb = *(const float4*)(b2 + gc);
            float o[4];
            float xs[4] = {bj.x + bi.x, bj.y + bi.y, bj.z + bi.z, bj.w + bi.w};
            float bbv[4] = {bb.x, bb.y, bb.z, bb.w};
            #pragma unroll
            for (int j = 0; j < 4; ++j)
                o[j] = xs[j] * racc[i][half * 4 + j] * (acc[i][half * 4 + j] + bbv[j]);
            *(float4*)(m_out + (size_t)gr * H3 + gc) =
                make_float4(o[0], o[1], o[2], o[3]);
        }
    }
}

// ---------------------------------------------------------------- scatter
__global__ __launch_bounds__(256)
void scatter_kernel(const float* __restrict__ m, const float* __restrict__ vec,
                    const int* __restrict__ ei, const float* __restrict__ ev,
                    const float* __restrict__ ec, float* __restrict__ dx,
                    float* __restrict__ dvec, int chunkOff, int Mrows) {
    int le = blockIdx.x * 2 + (threadIdx.x >> 7);
    int h  = threadIdx.x & 127;
    if (le >= Mrows) return;
    int e  = chunkOff + le;
    int jj = ei[e], ii = ei[E_EDGES + e];
    const float* mr = m + (size_t)le * H3;
    float x_m = mr[h];
    float xh2 = mr[HD + h] * INV_SQRT_3;
    float xh3 = mr[2 * HD + h];
    atomicAdd(&dx[(size_t)ii * HD + h], x_m);
    #pragma unroll
    for (int d = 0; d < 3; ++d) {
        float vm = vec[((size_t)jj * 3 + d) * HD + h] * xh2
                 + xh3 * ev[e * 3 + d] + x_m * ec[e * 3 + d];
        vm *= INV_SQRT_H;
        atomicAdd(&dvec[((size_t)ii * 3 + d) * HD + h], vm);
    }
}

// ---------------------------------------------------------------- launch
extern "C" void kernel_launch(void* const* d_in, const int* in_sizes, int n_in,
                              void* d_out, int out_size, void* d_ws, size_t ws_size,
                              hipStream_t stream) {
    const float* x        = (const float*)d_in[0];
    const float* vec      = (const float*)d_in[1];
    const int*   ei       = (const int*)d_in[2];
    const float* edge_rbf = (const float*)d_in[3];
    const float* weight   = (const float*)d_in[4];
    const float* ev       = (const float*)d_in[5];
    const float* ec       = (const float*)d_in[6];
    const float* ln_w     = (const float*)d_in[7];
    const float* ln_b     = (const float*)d_in[8];
    const float* xp_w1    = (const float*)d_in[9];
    const float* xp_w2    = (const float*)d_in[10];
    const float* rbf_w    = (const float*)d_in[11];
    const float* dir_w1   = (const float*)d_in[12];
    const float* dir_b1   = (const float*)d_in[13];
    const float* dir_w2   = (const float*)d_in[14];
    const float* dir_b2   = (const float*)d_in[15];

    float* ws   = (float*)d_ws;
    float* ln_x = ws;
    float* h1   = ln_x + (size_t)N_NODES * HD;
    float* xh   = h1 + (size_t)N_NODES * HD;
    float* d1   = xh + (size_t)N_NODES * H3;

    size_t usedF  = (size_t)N_NODES * (HD + HD + H3);
    size_t totF   = ws_size / 4;
    size_t availF = totF > usedF ? totF - usedF : 0;
    long long Cmax = (long long)(availF / (2 * H3));
    int C = (int)(Cmax & ~63LL);
    if (C > E_EDGES) C = E_EDGES;
    if (C < 64) C = 64;
    float* mbuf = d1 + (size_t)C * H3;

    hipMemsetAsync(d_out, 0, (size_t)out_size * sizeof(float), stream);
    float* dx   = (float*)d_out;
    float* dvec = dx + (size_t)N_NODES * HD;

    ln_kernel<<<(N_NODES + 3) / 4, 256, 0, stream>>>(x, ln_w, ln_b, ln_x);
    dim3 g1((N_NODES + 63) / 64, 1);
    gemm_tiled<1><<<g1, 256, 0, stream>>>(ln_x, xp_w1, nullptr, h1, N_NODES, HD, HD);
    dim3 g2((N_NODES + 63) / 64, 3);
    gemm_tiled<0><<<g2, 256, 0, stream>>>(h1, xp_w2, nullptr, xh, N_NODES, HD, H3);

    for (int off = 0; off < E_EDGES; off += C) {
        int rows = (E_EDGES - off < C) ? (E_EDGES - off) : C;
        dim3 ge((rows + 63) / 64, 3);
        gemm_tiled<2><<<ge, 256, 0, stream>>>(weight + (size_t)off * WIN, dir_w1,
                                              dir_b1, d1, rows, WIN, H3);
        edge2_fused<<<ge, 256, 0, stream>>>(d1, dir_w2, dir_b2, edge_rbf, rbf_w,
                                            xh, ei, mbuf, off, rows);
        scatter_kernel<<<(rows + 1) / 2, 256, 0, stream>>>(mbuf, vec, ei, ev, ec,
                                                           dx, dvec, off, rows);
    }
}

// Round 2
// 2497.377 us; speedup vs baseline: 2.0911x; 2.0911x over previous
//
#include <hip/hip_runtime.h>
#include <math.h>

#define N_NODES 20000
#define HD      128
#define H3      384
#define RDIM    32
#define E_EDGES 320000
#define WIN     416   // 3H + R

#define INV_SQRT_3 0.57735026918962576f
#define INV_SQRT_H 0.08838834764831845f

typedef __attribute__((ext_vector_type(8))) short s8v;   // 8 bf16 (4 VGPR) MFMA operand
typedef __attribute__((ext_vector_type(4))) short s4v;
typedef __attribute__((ext_vector_type(4))) float f4v;   // MFMA C/D

__device__ __forceinline__ float silu_f(float x) { return x / (1.0f + expf(-x)); }

// split f32 -> (hi,lo) bf16 pair packed in u32: low16 = hi-part, high16 = lo-part.
// hi truncated; lo captures remainder exactly up to its own rounding -> ~2^-16 rel.
__device__ __forceinline__ unsigned int splitpack(float x) {
    unsigned int u  = __float_as_uint(x);
    unsigned int hi = u >> 16;
    float rem = x - __uint_as_float(hi << 16);
    unsigned int lo = __float_as_uint(rem) >> 16;
    return hi | (lo << 16);
}

// ---------------------------------------------------------------- weight prep
// out[n*K + k] = splitpack(W[k*Nn + n])   (transpose + split)
__global__ __launch_bounds__(256)
void tsplit_kernel(const float* __restrict__ W, unsigned int* __restrict__ out,
                   int K, int Nn) {
    int i = blockIdx.x * 256 + threadIdx.x;
    if (i >= K * Nn) return;
    int n = i / K, k = i - n * K;
    out[i] = splitpack(W[(size_t)k * Nn + n]);
}

// elementwise split of edge weight chunk (row-major, same layout)
__global__ __launch_bounds__(256)
void split_kernel(const float* __restrict__ in, unsigned int* __restrict__ out, int n4) {
    int i = blockIdx.x * 256 + threadIdx.x;
    int stride = gridDim.x * 256;
    for (; i < n4; i += stride) {
        float4 v = ((const float4*)in)[i];
        uint4 o;
        o.x = splitpack(v.x); o.y = splitpack(v.y);
        o.z = splitpack(v.z); o.w = splitpack(v.w);
        ((uint4*)out)[i] = o;
    }
}

// ---------------------------------------------------------------- LayerNorm
__global__ __launch_bounds__(256)
void ln_kernel(const float* __restrict__ x, const float* __restrict__ w,
               const float* __restrict__ b, float* __restrict__ out) {
    int row  = blockIdx.x * 4 + (threadIdx.x >> 6);
    int lane = threadIdx.x & 63;
    if (row >= N_NODES) return;
    const float* xr = x + (size_t)row * HD;
    float v0 = xr[lane], v1 = xr[lane + 64];
    float s = v0 + v1;
    #pragma unroll
    for (int o = 32; o > 0; o >>= 1) s += __shfl_xor(s, o, 64);
    float mu = s * (1.0f / 128.0f);
    float d0 = v0 - mu, d1 = v1 - mu;
    float vs = d0 * d0 + d1 * d1;
    #pragma unroll
    for (int o = 32; o > 0; o >>= 1) vs += __shfl_xor(vs, o, 64);
    float rstd = rsqrtf(vs * (1.0f / 128.0f) + 1e-5f);
    out[(size_t)row * HD + lane]      = d0 * rstd * w[lane]      + b[lane];
    out[(size_t)row * HD + lane + 64] = d1 * rstd * w[lane + 64] + b[lane + 64];
}

// ---------------------------------------------------------------- f32 GEMM (node path)
template<int EPI>   // 0 none, 1 silu
__global__ __launch_bounds__(256)
void gemm_tiled(const float* __restrict__ A, const float* __restrict__ B,
                const float* __restrict__ bias, float* __restrict__ C,
                int M, int K, int Nfull) {
    __shared__ float As[64][36];
    __shared__ float Bs[32][128];
    const int rowBase = blockIdx.x * 64;
    const int colBase = blockIdx.y * 128;
    const int tid = threadIdx.x;
    const int ty4 = (tid >> 4) << 2;
    const int txc = (tid & 15) << 2;

    float acc[4][8];
    #pragma unroll
    for (int i = 0; i < 4; ++i)
        #pragma unroll
        for (int j = 0; j < 8; ++j) acc[i][j] = 0.0f;

    const int nK = K >> 5;
    for (int ko = 0; ko < nK; ++ko) {
        const int kBase = ko << 5;
        #pragma unroll
        for (int q = 0; q < 2; ++q) {
            int v = tid + (q << 8);
            int r = v >> 3, c4 = (v & 7) << 2;
            float4 val = make_float4(0.f, 0.f, 0.f, 0.f);
            int gr = rowBase + r;
            if (gr < M) val = *(const float4*)(A + (size_t)gr * K + kBase + c4);
            *(float4*)&As[r][c4] = val;
        }
        #pragma unroll
        for (int q = 0; q < 4; ++q) {
            int v = tid + (q << 8);
            int r = v >> 5, c4 = (v & 31) << 2;
            *(float4*)&Bs[r][c4] =
                *(const float4*)(B + (size_t)(kBase + r) * Nfull + colBase + c4);
        }
        __syncthreads();
        #pragma unroll
        for (int k = 0; k < 32; ++k) {
            float av[4];
            #pragma unroll
            for (int i = 0; i < 4; ++i) av[i] = As[ty4 + i][k];
            float bv[8];
            *(float4*)&bv[0] = *(const float4*)&Bs[k][txc];
            *(float4*)&bv[4] = *(const float4*)&Bs[k][txc + 64];
            #pragma unroll
            for (int i = 0; i < 4; ++i)
                #pragma unroll
                for (int j = 0; j < 8; ++j)
                    acc[i][j] = fmaf(av[i], bv[j], acc[i][j]);
        }
        __syncthreads();
    }
    #pragma unroll
    for (int i = 0; i < 4; ++i) {
        int gr = rowBase + ty4 + i;
        if (gr >= M) continue;
        #pragma unroll
        for (int half = 0; half < 2; ++half) {
            int gc = colBase + txc + half * 64;
            float o[4];
            #pragma unroll
            for (int j = 0; j < 4; ++j) {
                float v = acc[i][half * 4 + j];
                if (EPI >= 1) v = silu_f(v);
                o[j] = v;
            }
            *(float4*)(C + (size_t)gr * Nfull + gc) = make_float4(o[0], o[1], o[2], o[3]);
        }
    }
}

// ---------------------------------------------------------------- MFMA split-bf16 GEMM
// LDS plane layout: [128 rows][32 shorts]; k -> col = (k&3) + 4*((k>>4)&1) + 8*((k>>2)&3)
// so one 16B slot (8 shorts) per (row, lane-group) is a complete fragment k-group.
// 16B slots XOR-swizzled by row&3 to break bank alignment.
__device__ __forceinline__ int lidx(int r, int s) {
    return r * 32 + (((s ^ (r & 3)) << 3));
}

template<bool F32SRC>
__device__ __forceinline__ void stage_tile(const void* __restrict__ src, int srcStride,
                                           int rowBase, int Mrows, int kBase,
                                           short* __restrict__ pHi, short* __restrict__ pLo,
                                           int tid) {
    int r = tid >> 1, h = tid & 1;        // thread covers row r, k = kBase + 16h .. +15
    int gr = rowBase + r;
    uint4 q[4];
    if (gr < Mrows) {
        if (F32SRC) {
            const float* p = (const float*)src + (size_t)gr * srcStride + kBase + h * 16;
            #pragma unroll
            for (int a = 0; a < 4; ++a) {
                float4 f = ((const float4*)p)[a];
                q[a].x = splitpack(f.x); q[a].y = splitpack(f.y);
                q[a].z = splitpack(f.z); q[a].w = splitpack(f.w);
            }
        } else {
            const unsigned int* p = (const unsigned int*)src + (size_t)gr * srcStride + kBase + h * 16;
            #pragma unroll
            for (int a = 0; a < 4; ++a) q[a] = ((const uint4*)p)[a];
        }
    } else {
        #pragma unroll
        for (int a = 0; a < 4; ++a) q[a] = make_uint4(0, 0, 0, 0);
    }
    #pragma unroll
    for (int a = 0; a < 4; ++a) {        // uint4 a holds k = 16h + 4a + {0..3} -> slot a, half h
        s4v hi4, lo4;
        hi4[0] = (short)(q[a].x & 0xffff); hi4[1] = (short)(q[a].y & 0xffff);
        hi4[2] = (short)(q[a].z & 0xffff); hi4[3] = (short)(q[a].w & 0xffff);
        lo4[0] = (short)(q[a].x >> 16);    lo4[1] = (short)(q[a].y >> 16);
        lo4[2] = (short)(q[a].z >> 16);    lo4[3] = (short)(q[a].w >> 16);
        int idx = lidx(r, a) + (h << 2);
        *(s4v*)&pHi[idx] = hi4;
        *(s4v*)&pLo[idx] = lo4;
    }
}

// MODE 0: d1p = splitpack(silu(Apk @ Bpk + bias))          (A=wsplit, B=w1t, K=416)
// MODE 1: mbuf = (xh[jj]+xh[ii]) * (rbf@rbfw) * (Apk@Bpk + bias)   (A=d1p, B=w2t, K=384)
template<int MODE>
__global__ __launch_bounds__(256, 2)
void mfma_gemm(const unsigned int* __restrict__ Ap, const unsigned int* __restrict__ Bp,
               int K, int Mrows, const float* __restrict__ bias,
               unsigned int* __restrict__ d1p,
               const float* __restrict__ edge_rbf, const unsigned int* __restrict__ rbfwt,
               const float* __restrict__ xh, const int* __restrict__ ei,
               float* __restrict__ mbuf, int chunkOff) {
    __shared__ short lds[4][128 * 32];   // A_hi, A_lo, B_hi, B_lo : 32 KiB
    const int tid  = threadIdx.x;
    const int lane = tid & 63;
    const int wid  = tid >> 6;
    const int wm = wid >> 1, wn = wid & 1;   // 2x2 waves, 64x64 each
    const int lr = lane & 15, lk = lane >> 4;
    const int rowBase = blockIdx.x * 128;
    const int colBase = blockIdx.y * 128;

    f4v acc[4][4];
    #pragma unroll
    for (int i = 0; i < 4; ++i)
        #pragma unroll
        for (int j = 0; j < 4; ++j) acc[i][j] = (f4v){0.f, 0.f, 0.f, 0.f};
    f4v racc[4][4];
    if (MODE == 1) {
        #pragma unroll
        for (int i = 0; i < 4; ++i)
            #pragma unroll
            for (int j = 0; j < 4; ++j) racc[i][j] = (f4v){0.f, 0.f, 0.f, 0.f};
    }

    const int nK = K >> 5;
    for (int ks = 0; ks < nK; ++ks) {
        const int kBase = ks << 5;
        stage_tile<false>(Ap, K, rowBase, Mrows, kBase, lds[0], lds[1], tid);
        stage_tile<false>(Bp, K, colBase, 1 << 30, kBase, lds[2], lds[3], tid);
        __syncthreads();
        s8v ah[4], al[4], bh[4], bl[4];
        #pragma unroll
        for (int f = 0; f < 4; ++f) {
            int ra = wm * 64 + f * 16 + lr;
            ah[f] = *(const s8v*)&lds[0][lidx(ra, lk)];
            al[f] = *(const s8v*)&lds[1][lidx(ra, lk)];
            int rb = wn * 64 + f * 16 + lr;
            bh[f] = *(const s8v*)&lds[2][lidx(rb, lk)];
            bl[f] = *(const s8v*)&lds[3][lidx(rb, lk)];
        }
        #pragma unroll
        for (int i = 0; i < 4; ++i)
            #pragma unroll
            for (int j = 0; j < 4; ++j) {
                acc[i][j] = __builtin_amdgcn_mfma_f32_16x16x32_bf16(ah[i], bh[j], acc[i][j], 0, 0, 0);
                acc[i][j] = __builtin_amdgcn_mfma_f32_16x16x32_bf16(al[i], bh[j], acc[i][j], 0, 0, 0);
                acc[i][j] = __builtin_amdgcn_mfma_f32_16x16x32_bf16(ah[i], bl[j], acc[i][j], 0, 0, 0);
            }
        __syncthreads();
    }

    if (MODE == 1) {
        // one extra K-step: racc = edge_rbf @ rbf_w   (A f32 on the fly, B pre-split)
        stage_tile<true >(edge_rbf + (size_t)chunkOff * RDIM, RDIM, rowBase, Mrows, 0,
                          lds[0], lds[1], tid);
        stage_tile<false>(rbfwt, RDIM, colBase, 1 << 30, 0, lds[2], lds[3], tid);
        __syncthreads();
        s8v ah[4], al[4], bh[4], bl[4];
        #pragma unroll
        for (int f = 0; f < 4; ++f) {
            int ra = wm * 64 + f * 16 + lr;
            ah[f] = *(const s8v*)&lds[0][lidx(ra, lk)];
            al[f] = *(const s8v*)&lds[1][lidx(ra, lk)];
            int rb = wn * 64 + f * 16 + lr;
            bh[f] = *(const s8v*)&lds[2][lidx(rb, lk)];
            bl[f] = *(const s8v*)&lds[3][lidx(rb, lk)];
        }
        #pragma unroll
        for (int i = 0; i < 4; ++i)
            #pragma unroll
            for (int j = 0; j < 4; ++j) {
                racc[i][j] = __builtin_amdgcn_mfma_f32_16x16x32_bf16(ah[i], bh[j], racc[i][j], 0, 0, 0);
                racc[i][j] = __builtin_amdgcn_mfma_f32_16x16x32_bf16(al[i], bh[j], racc[i][j], 0, 0, 0);
                racc[i][j] = __builtin_amdgcn_mfma_f32_16x16x32_bf16(ah[i], bl[j], racc[i][j], 0, 0, 0);
            }
    }

    // epilogue. C/D: col = lane&15, row = 4*(lane>>4)+reg  [guide-verified]
    float bcol[4];
    #pragma unroll
    for (int j = 0; j < 4; ++j) bcol[j] = bias[colBase + wn * 64 + j * 16 + lr];

    #pragma unroll
    for (int i = 0; i < 4; ++i)
        #pragma unroll
        for (int q = 0; q < 4; ++q) {
            int grl = rowBase + wm * 64 + i * 16 + 4 * lk + q;
            if (grl >= Mrows) continue;
            if (MODE == 0) {
                #pragma unroll
                for (int j = 0; j < 4; ++j) {
                    int c = colBase + wn * 64 + j * 16 + lr;
                    float v = silu_f(acc[i][j][q] + bcol[j]);
                    d1p[(size_t)grl * H3 + c] = splitpack(v);
                }
            } else {
                int e  = chunkOff + grl;
                int jj = ei[e], ii = ei[E_EDGES + e];
                const float* xj = xh + (size_t)jj * H3 + colBase + wn * 64;
                const float* xi = xh + (size_t)ii * H3 + colBase + wn * 64;
                float* mrow = mbuf + (size_t)grl * H3 + colBase + wn * 64;
                #pragma unroll
                for (int j = 0; j < 4; ++j) {
                    int c = j * 16 + lr;
                    float xs = xj[c] + xi[c];
                    mrow[c] = xs * racc[i][j][q] * (acc[i][j][q] + bcol[j]);
                }
            }
        }
}

// ---------------------------------------------------------------- scatter
__global__ __launch_bounds__(256)
void scatter_kernel(const float* __restrict__ m, const float* __restrict__ vec,
                    const int* __restrict__ ei, const float* __restrict__ ev,
                    const float* __restrict__ ec, float* __restrict__ dx,
                    float* __restrict__ dvec, int chunkOff, int Mrows) {
    int le = blockIdx.x * 2 + (threadIdx.x >> 7);
    int h  = threadIdx.x & 127;
    if (le >= Mrows) return;
    int e  = chunkOff + le;
    int jj = ei[e], ii = ei[E_EDGES + e];
    const float* mr = m + (size_t)le * H3;
    float x_m = mr[h];
    float xh2 = mr[HD + h] * INV_SQRT_3;
    float xh3 = mr[2 * HD + h];
    atomicAdd(&dx[(size_t)ii * HD + h], x_m);
    #pragma unroll
    for (int d = 0; d < 3; ++d) {
        float vm = vec[((size_t)jj * 3 + d) * HD + h] * xh2
                 + xh3 * ev[e * 3 + d] + x_m * ec[e * 3 + d];
        vm *= INV_SQRT_H;
        atomicAdd(&dvec[((size_t)ii * 3 + d) * HD + h], vm);
    }
}

// ---------------------------------------------------------------- launch
extern "C" void kernel_launch(void* const* d_in, const int* in_sizes, int n_in,
                              void* d_out, int out_size, void* d_ws, size_t ws_size,
                              hipStream_t stream) {
    const float* x        = (const float*)d_in[0];
    const float* vec      = (const float*)d_in[1];
    const int*   ei       = (const int*)d_in[2];
    const float* edge_rbf = (const float*)d_in[3];
    const float* weight   = (const float*)d_in[4];
    const float* ev       = (const float*)d_in[5];
    const float* ec       = (const float*)d_in[6];
    const float* ln_w     = (const float*)d_in[7];
    const float* ln_b     = (const float*)d_in[8];
    const float* xp_w1    = (const float*)d_in[9];
    const float* xp_w2    = (const float*)d_in[10];
    const float* rbf_w    = (const float*)d_in[11];
    const float* dir_w1   = (const float*)d_in[12];
    const float* dir_b1   = (const float*)d_in[13];
    const float* dir_w2   = (const float*)d_in[14];
    const float* dir_b2   = (const float*)d_in[15];

    float* ws   = (float*)d_ws;
    float* ln_x = ws;
    float* h1   = ln_x + (size_t)N_NODES * HD;
    float* xh   = h1 + (size_t)N_NODES * HD;
    unsigned int* w1t   = (unsigned int*)(xh + (size_t)N_NODES * H3);
    unsigned int* w2t   = w1t + (size_t)H3 * WIN;
    unsigned int* rbfwt = w2t + (size_t)H3 * H3;
    unsigned int* chunkBase = rbfwt + (size_t)H3 * RDIM;

    size_t fixedW = (size_t)N_NODES * (HD + HD + H3)
                  + (size_t)H3 * WIN + (size_t)H3 * H3 + (size_t)H3 * RDIM;
    size_t totW   = ws_size / 4;
    size_t availW = totW > fixedW ? totW - fixedW : 0;
    long long Cmax = (long long)(availW / (WIN + H3 + H3));
    int C = (int)(Cmax & ~127LL);
    if (C > E_EDGES) C = E_EDGES;
    if (C < 128) C = 128;
    unsigned int* wsplit = chunkBase;
    unsigned int* d1p    = wsplit + (size_t)C * WIN;
    float*        mbuf   = (float*)(d1p + (size_t)C * H3);

    hipMemsetAsync(d_out, 0, (size_t)out_size * sizeof(float), stream);
    float* dx   = (float*)d_out;
    float* dvec = dx + (size_t)N_NODES * HD;

    // weight prep (tiny)
    tsplit_kernel<<<(H3 * WIN + 255) / 256, 256, 0, stream>>>(dir_w1, w1t, WIN, H3);
    tsplit_kernel<<<(H3 * H3 + 255) / 256, 256, 0, stream>>>(dir_w2, w2t, H3, H3);
    tsplit_kernel<<<(H3 * RDIM + 255) / 256, 256, 0, stream>>>(rbf_w, rbfwt, RDIM, H3);

    // node path (f32, small)
    ln_kernel<<<(N_NODES + 3) / 4, 256, 0, stream>>>(x, ln_w, ln_b, ln_x);
    gemm_tiled<1><<<dim3((N_NODES + 63) / 64, 1), 256, 0, stream>>>(ln_x, xp_w1, nullptr, h1, N_NODES, HD, HD);
    gemm_tiled<0><<<dim3((N_NODES + 63) / 64, 3), 256, 0, stream>>>(h1, xp_w2, nullptr, xh, N_NODES, HD, H3);

    for (int off = 0; off < E_EDGES; off += C) {
        int rows = (E_EDGES - off < C) ? (E_EDGES - off) : C;
        int n4 = rows * WIN / 4;
        split_kernel<<<2048, 256, 0, stream>>>(weight + (size_t)off * WIN, wsplit, n4);
        dim3 ge((rows + 127) / 128, 3);
        mfma_gemm<0><<<ge, 256, 0, stream>>>(wsplit, w1t, WIN, rows, dir_b1, d1p,
                                             nullptr, nullptr, nullptr, nullptr, nullptr, 0);
        mfma_gemm<1><<<ge, 256, 0, stream>>>(d1p, w2t, H3, rows, dir_b2, nullptr,
                                             edge_rbf, rbfwt, xh, ei, mbuf, off);
        scatter_kernel<<<(rows + 1) / 2, 256, 0, stream>>>(mbuf, vec, ei, ev, ec,
                                                           dx, dvec, off, rows);
    }
}